// Round 21
// baseline (248.073 us; speedup 1.0000x reference)
//
#include <hip/hip_runtime.h>
#include <hip/hip_bf16.h>

#define N_NODES 100000
#define N_EDGES 1000000
#define DIM 64

static const long long ND = (long long)N_NODES * DIM;  // 6,400,000

typedef float f4_t __attribute__((ext_vector_type(4)));
typedef unsigned u4_t __attribute__((ext_vector_type(4)));
typedef short s8_t __attribute__((ext_vector_type(8)));   // 8 bf16 (4 VGPRs)

// d_out layout (floats):
// h1: [0, ND)  h2: [ND, 2*ND)  c1c2: [2*ND, 2*ND+128)  h3: [2*ND+128, ...)  h4: [3*ND+128, ...)

#define NBUCK 98                   // buckets of 1024 nodes; 98*1024 >= 100000
#define BCAP 13312                 // fixed bucket region (mean 10240, sd ~101; +30 sigma)
#define OFFSTR 1028                // per-bucket off-table stride (16B aligned; 1025 used)

// d_ws layout (4-byte words):
#define WS_OFF1  200000            // 98*1028 = 100744
#define WS_OFF2  300744
#define WS_SORT1 401488            // 98*13312 = 1,304,576 (payloads then sorted src ids)
#define WS_SORT2 1706064
#define WS_CSUM  3010640           // 128 floats
#define WS_BCUR  3010768           // 196 zero-based partition cursors
#define WS_WBT   3010964           // bf16 W^T: WbT[g][col][k], 8192 ushort = 4096 words
#define WS_FBSB  3015060           // interleaved bf16 rows: [FB(128B) | SB(128B)] per node
#define WS_END   (WS_FBSB + 6400000) // ~37.7 MB

#define CH_CONV 3125               // convert blocks: 3125*256*16 floats = 12.8M
#define CH_PARTG 489               // partition blocks per graph: 489*512 int4 >= 250000

__device__ __forceinline__ unsigned pk_bf16(float a, float b) {
    __hip_bfloat16 ha = __float2bfloat16(a), hb = __float2bfloat16(b);
    return (unsigned)(*(unsigned short*)&ha) | ((unsigned)(*(unsigned short*)&hb) << 16);
}
__device__ __forceinline__ float bf_lo(unsigned u) { return __uint_as_float(u << 16); }
__device__ __forceinline__ float bf_hi(unsigned u) { return __uint_as_float(u & 0xFFFF0000u); }

__global__ __launch_bounds__(256) void k_init(int* __restrict__ ws,
                                              const float* __restrict__ W1,
                                              const float* __restrict__ W2) {
    const int t = threadIdx.x;
    if (t < 128) ((float*)ws)[WS_CSUM + t] = 0.f;
    if (t < 196) ws[WS_BCUR + t] = 0;
    // W -> bf16 transposed: WbT[g][col][k]
    unsigned short* wbt = (unsigned short*)(ws + WS_WBT);
    for (int i = t; i < 8192; i += 256) {
        const int g = i >> 12, e = i & 4095;
        const int col = e >> 6, k = e & 63;
        const float* Wsrc = g ? W2 : W1;
        __hip_bfloat16 hb = __float2bfloat16(Wsrc[k * 64 + col]);
        wbt[i] = *(unsigned short*)&hb;
    }
}

// FUSED f32->bf16 convert (into interleaved FBSB rows) + partition.
__global__ __launch_bounds__(256) void k_convert_partition(
    const f4_t* __restrict__ feat4, const f4_t* __restrict__ shuf4,
    const int4* __restrict__ src1, const int4* __restrict__ dst1,
    const int4* __restrict__ src2, const int4* __restrict__ dst2,
    int* __restrict__ ws) {
    const int bid = blockIdx.x;
    const int t = threadIdx.x;
    if (bid < CH_CONV) {
        // ---------------- convert ----------------
        const long long NF4 = ND / 4;               // 1.6M f4 per array
        const long long base = ((long long)bid * 256 + t) * 4;
        uint2* T2 = (uint2*)(ws + WS_FBSB);         // row = 32 uint2 (256B)
        #pragma unroll
        for (int k = 0; k < 4; ++k) {
            const long long j = base + k;
            if (j < NF4) {
                const f4_t v = __builtin_nontemporal_load(feat4 + j);
                const long long n = j >> 4, c = j & 15;
                T2[n * 32 + c] = make_uint2(pk_bf16(v.x, v.y), pk_bf16(v.z, v.w));
            } else if (j < 2 * NF4) {
                const long long jj = j - NF4;
                const f4_t v = __builtin_nontemporal_load(shuf4 + jj);
                const long long n = jj >> 4, c = jj & 15;
                T2[n * 32 + 16 + c] = make_uint2(pk_bf16(v.x, v.y), pk_bf16(v.z, v.w));
            }
        }
    } else {
        // ---------------- partition ----------------
        const int pid = bid - CH_CONV;
        const int g = pid >= CH_PARTG;
        const int px = g ? pid - CH_PARTG : pid;
        __shared__ int lcnt[NBUCK];
        __shared__ int lbase[NBUCK];
        const int4* sv4 = g ? src2 : src1;
        const int4* dv4 = g ? dst2 : dst1;
        int* sortp = ws + (g ? WS_SORT2 : WS_SORT1);
        int* bcur = ws + WS_BCUR + g * NBUCK;
        const int Q = N_EDGES / 4;

        const int q0 = px * 512 + t;
        const int q1 = q0 + 256;
        const bool v0 = q0 < Q, v1 = q1 < Q;
        int4 s0, d0, s1, d1;
        if (v0) { s0 = sv4[q0]; d0 = dv4[q0]; }
        if (v1) { s1 = sv4[q1]; d1 = dv4[q1]; }

        for (int i = t; i < NBUCK; i += 256) lcnt[i] = 0;
        __syncthreads();
        if (v0) {
            atomicAdd(&lcnt[d0.x >> 10], 1); atomicAdd(&lcnt[d0.y >> 10], 1);
            atomicAdd(&lcnt[d0.z >> 10], 1); atomicAdd(&lcnt[d0.w >> 10], 1);
        }
        if (v1) {
            atomicAdd(&lcnt[d1.x >> 10], 1); atomicAdd(&lcnt[d1.y >> 10], 1);
            atomicAdd(&lcnt[d1.z >> 10], 1); atomicAdd(&lcnt[d1.w >> 10], 1);
        }
        __syncthreads();
        if (t < NBUCK) lbase[t] = lcnt[t] ? t * BCAP + atomicAdd(&bcur[t], lcnt[t]) : 0;
        __syncthreads();

#define PUT(ss, dd) { const int b_ = (dd) >> 10; \
    const int pos_ = atomicAdd(&lbase[b_], 1); \
    sortp[pos_] = (ss) | (((dd) & 1023) << 17); }
        if (v0) { PUT(s0.x, d0.x); PUT(s0.y, d0.y); PUT(s0.z, d0.z); PUT(s0.w, d0.w); }
        if (v1) { PUT(s1.x, d1.x); PUT(s1.y, d1.y); PUT(s1.z, d1.z); PUT(s1.w, d1.w); }
#undef PUT
    }
}

// Place: one block per (bucket, graph).
__global__ __launch_bounds__(256) void k_place(int* __restrict__ ws) {
    const int g = blockIdx.y;
    const int b = blockIdx.x;
    const int t = threadIdx.x;
    __shared__ int pl[BCAP];
    __shared__ int lcur[1024];
    __shared__ int sscan[256];

    const int base = b * BCAP;
    int cnt = ws[WS_BCUR + g * NBUCK + b];
    if (cnt > BCAP) cnt = BCAP;
    int* sortp = ws + (g ? WS_SORT2 : WS_SORT1);
    int* off = ws + (g ? WS_OFF2 : WS_OFF1) + b * OFFSTR;

    for (int i = t; i < cnt; i += 256) pl[i] = sortp[base + i];
    for (int i = t; i < 1024; i += 256) lcur[i] = 0;
    __syncthreads();
    for (int i = t; i < cnt; i += 256) atomicAdd(&lcur[(pl[i] >> 17) & 1023], 1);
    __syncthreads();

    const int c0 = lcur[4 * t], c1 = lcur[4 * t + 1], c2 = lcur[4 * t + 2], c3 = lcur[4 * t + 3];
    sscan[t] = c0 + c1 + c2 + c3;
    __syncthreads();
    for (int d = 1; d < 256; d <<= 1) {
        int v = 0;
        if (t >= d) v = sscan[t - d];
        __syncthreads();
        sscan[t] += v;
        __syncthreads();
    }
    const int excl = (t == 0) ? 0 : sscan[t - 1];
    const int p0 = base + excl, p1 = p0 + c0, p2 = p1 + c1, p3 = p2 + c2;
    lcur[4 * t] = p0; lcur[4 * t + 1] = p1; lcur[4 * t + 2] = p2; lcur[4 * t + 3] = p3;
    *(int4*)(off + 4 * t) = make_int4(p0, p1, p2, p3);   // off[0..1023]
    if (t == 255) off[1024] = base + cnt;                // bucket end sentinel
    __syncthreads();
    for (int i = t; i < cnt; i += 256) {
        const int p = pl[i];
        const int pos = atomicAdd(&lcur[(p >> 17) & 1023], 1);
        sortp[pos] = p & 0x1FFFF;
    }
}

// FUSED gather + MFMA transform. Phase 1: gather interleaved FBSB rows, one
// node per 8-lane group, 32 nodes/block (grid exact: 3125*32 = 100000), agg in
// registers -> packed bf16 into padded LDS tiles (stride 144B, no 16-way bank
// conflict on the MFMA frag reads). Phase 2: B-frags (32 VGPR, loaded AFTER
// the barrier so they don't stack on the gather's live range -- the R14
// lesson), waves 0-1 MFMA the 32 feat rows -> h_f + csum, waves 2-3 the shuf
// rows -> h_s. Kills k_htrans_mfma and the 102MB agg round-trip.
#define ACC2(gv, sv) \
    ag[0] += bf_lo(gv.x); ag[1] += bf_hi(gv.x); \
    ag[2] += bf_lo(gv.y); ag[3] += bf_hi(gv.y); \
    ag[4] += bf_lo(gv.z); ag[5] += bf_hi(gv.z); \
    ag[6] += bf_lo(gv.w); ag[7] += bf_hi(gv.w); \
    as[0] += bf_lo(sv.x); as[1] += bf_hi(sv.x); \
    as[2] += bf_lo(sv.y); as[3] += bf_hi(sv.y); \
    as[4] += bf_lo(sv.z); as[5] += bf_hi(sv.z); \
    as[6] += bf_lo(sv.w); as[7] += bf_hi(sv.w);

__global__ __launch_bounds__(256) void k_gather_trans(int* __restrict__ ws,
                                                      const float* __restrict__ b1,
                                                      const float* __restrict__ b2,
                                                      float* __restrict__ out) {
    const int g = blockIdx.y;
    const int* offT   = ws + (g ? WS_OFF2 : WS_OFF1);
    const int* sorted = ws + (g ? WS_SORT2 : WS_SORT1);
    const uint4* T = (const uint4*)(ws + WS_FBSB);   // 16 uint4 per row
    const float* bias = g ? b2 : b1;
    const s8_t* WT = (const s8_t*)((const unsigned short*)(ws + WS_WBT) + g * 4096);
    float* h_f = out + (g ? ND : 0);
    float* h_s = out + (g ? 3 * ND + 128 : 2 * ND + 128);
    float* csum = (float*)ws + WS_CSUM + g * 64;

    __shared__ unsigned Af[32][36];   // 32 rows x 8 u4 + 1 u4 pad (144B stride)
    __shared__ unsigned As_[32][36];
    __shared__ float red[2][64];

    const int t = threadIdx.x;
    const int wave = t >> 6;
    const int lane = t & 63;
    const int nslot = lane >> 3;
    const int sub = lane & 7;

    const int n0 = blockIdx.x * 32;
    const int lrow = wave * 8 + nslot;
    const int n = n0 + lrow;               // always < N_NODES (exact grid)

    float ag[8] = {0.f, 0.f, 0.f, 0.f, 0.f, 0.f, 0.f, 0.f};
    float as[8] = {0.f, 0.f, 0.f, 0.f, 0.f, 0.f, 0.f, 0.f};

    const int* offb = offT + (n >> 10) * OFFSTR + (n & 1023);
    const int e0 = offb[0];
    const int e1 = offb[1];
    int e = e0;
    for (; e + 7 < e1; e += 8) {
        const int sA = sorted[e],     sB = sorted[e + 1];
        const int sC = sorted[e + 2], sD = sorted[e + 3];
        const int sE = sorted[e + 4], sF = sorted[e + 5];
        const int sG = sorted[e + 6], sH = sorted[e + 7];
        const uint4 gA = T[sA * 16 + sub], hA = T[sA * 16 + 8 + sub];
        const uint4 gB = T[sB * 16 + sub], hB = T[sB * 16 + 8 + sub];
        const uint4 gC = T[sC * 16 + sub], hC = T[sC * 16 + 8 + sub];
        const uint4 gD = T[sD * 16 + sub], hD = T[sD * 16 + 8 + sub];
        const uint4 gE = T[sE * 16 + sub], hE = T[sE * 16 + 8 + sub];
        const uint4 gF = T[sF * 16 + sub], hF = T[sF * 16 + 8 + sub];
        const uint4 gG = T[sG * 16 + sub], hG = T[sG * 16 + 8 + sub];
        const uint4 gH = T[sH * 16 + sub], hH = T[sH * 16 + 8 + sub];
        ACC2(gA, hA); ACC2(gB, hB); ACC2(gC, hC); ACC2(gD, hD);
        ACC2(gE, hE); ACC2(gF, hF); ACC2(gG, hG); ACC2(gH, hH);
    }
    for (; e + 3 < e1; e += 4) {
        const int sA = sorted[e],     sB = sorted[e + 1];
        const int sC = sorted[e + 2], sD = sorted[e + 3];
        const uint4 gA = T[sA * 16 + sub], hA = T[sA * 16 + 8 + sub];
        const uint4 gB = T[sB * 16 + sub], hB = T[sB * 16 + 8 + sub];
        const uint4 gC = T[sC * 16 + sub], hC = T[sC * 16 + 8 + sub];
        const uint4 gD = T[sD * 16 + sub], hD = T[sD * 16 + 8 + sub];
        ACC2(gA, hA); ACC2(gB, hB); ACC2(gC, hC); ACC2(gD, hD);
    }
    for (; e < e1; ++e) {
        const int s = sorted[e];
        const uint4 gv = T[s * 16 + sub], hv = T[s * 16 + 8 + sub];
        ACC2(gv, hv);
    }

    // pack agg to bf16 and stage into LDS tiles
    u4_t pf;
    pf.x = pk_bf16(ag[0], ag[1]); pf.y = pk_bf16(ag[2], ag[3]);
    pf.z = pk_bf16(ag[4], ag[5]); pf.w = pk_bf16(ag[6], ag[7]);
    *(u4_t*)&Af[lrow][sub * 4] = pf;
    u4_t ps;
    ps.x = pk_bf16(as[0], as[1]); ps.y = pk_bf16(as[2], as[3]);
    ps.z = pk_bf16(as[4], as[5]); ps.w = pk_bf16(as[6], as[7]);
    *(u4_t*)&As_[lrow][sub * 4] = ps;
    __syncthreads();

    // ---------------- MFMA transform ----------------
    const int lm = lane & 15;
    const int lh = lane >> 4;

    s8_t bfr[4][2];
    #pragma unroll
    for (int nt = 0; nt < 4; ++nt) {
        bfr[nt][0] = WT[(nt * 16 + lm) * 8 + lh];
        bfr[nt][1] = WT[(nt * 16 + lm) * 8 + 4 + lh];
    }
    float bs[4];
    #pragma unroll
    for (int nt = 0; nt < 4; ++nt) bs[nt] = bias[nt * 16 + lm];

    const bool isf = wave < 2;
    const int rbase = (wave & 1) * 16;
    const unsigned (*A)[36] = isf ? Af : As_;
    float* harr = isf ? h_f : h_s;

    const s8_t a0 = *(const s8_t*)&A[rbase + lm][lh * 4];       // k = 0..31
    const s8_t a1 = *(const s8_t*)&A[rbase + lm][16 + lh * 4];  // k = 32..63

    f4_t acc[4];
    #pragma unroll
    for (int nt = 0; nt < 4; ++nt) {
        acc[nt] = (f4_t){0.f, 0.f, 0.f, 0.f};
        acc[nt] = __builtin_amdgcn_mfma_f32_16x16x32_bf16(a0, bfr[nt][0], acc[nt], 0, 0, 0);
        acc[nt] = __builtin_amdgcn_mfma_f32_16x16x32_bf16(a1, bfr[nt][1], acc[nt], 0, 0, 0);
    }

    float csloc[4] = {0.f, 0.f, 0.f, 0.f};
    #pragma unroll
    for (int nt = 0; nt < 4; ++nt) {
        #pragma unroll
        for (int i = 0; i < 4; ++i) {
            const int row = rbase + 4 * lh + i;
            const float v = acc[nt][i] + bs[nt];
            harr[(long long)(n0 + row) * DIM + nt * 16 + lm] = v;
            csloc[nt] += v;
        }
    }

    // csum over h1/h2 (feat waves only)
    if (isf) {
        #pragma unroll
        for (int nt = 0; nt < 4; ++nt) {
            csloc[nt] += __shfl_xor(csloc[nt], 16);
            csloc[nt] += __shfl_xor(csloc[nt], 32);
        }
        if (lane < 16) {
            #pragma unroll
            for (int nt = 0; nt < 4; ++nt) red[wave][nt * 16 + lane] = csloc[nt];
        }
    }
    __syncthreads();
    if (t < 64) {
        const float s = red[0][t] + red[1][t];
        unsafeAtomicAdd(&csum[t], s);
    }
}

__global__ void k_final(const float* __restrict__ ws_csum, float* __restrict__ out_c) {
    int t = threadIdx.x;  // 0..63 -> c1, 64..127 -> c2
    float m = ws_csum[t] * (1.0f / (float)N_NODES);
    out_c[t] = 1.f / (1.f + expf(-m));
}

extern "C" void kernel_launch(void* const* d_in, const int* in_sizes, int n_in,
                              void* d_out, int out_size, void* d_ws, size_t ws_size,
                              hipStream_t stream) {
    const float* feat = (const float*)d_in[0];
    const float* shuf = (const float*)d_in[1];
    const int* src1 = (const int*)d_in[2];
    const int* dst1 = (const int*)d_in[3];
    const int* src2 = (const int*)d_in[4];
    const int* dst2 = (const int*)d_in[5];
    const float* W1 = (const float*)d_in[6];
    const float* b1 = (const float*)d_in[7];
    const float* W2 = (const float*)d_in[8];
    const float* b2 = (const float*)d_in[9];

    float* out = (float*)d_out;
    int* ws = (int*)d_ws;
    float* ws_f = (float*)d_ws;
    float* c_out = out + 2 * ND;

    k_init<<<1, 256, 0, stream>>>(ws, W1, W2);
    k_convert_partition<<<CH_CONV + 2 * CH_PARTG, 256, 0, stream>>>(
        (const f4_t*)feat, (const f4_t*)shuf,
        (const int4*)src1, (const int4*)dst1, (const int4*)src2, (const int4*)dst2, ws);
    k_place<<<dim3(NBUCK, 2), 256, 0, stream>>>(ws);
    k_gather_trans<<<dim3(N_NODES / 32, 2), 256, 0, stream>>>(ws, b1, b2, out);
    k_final<<<1, 128, 0, stream>>>(ws_f + WS_CSUM, c_out);
}

// Round 22
// 226.000 us; speedup vs baseline: 1.0977x; 1.0977x over previous
//
#include <hip/hip_runtime.h>
#include <hip/hip_bf16.h>

#define N_NODES 100000
#define N_EDGES 1000000
#define DIM 64

static const long long ND = (long long)N_NODES * DIM;  // 6,400,000

typedef float f4_t __attribute__((ext_vector_type(4)));
typedef unsigned u4_t __attribute__((ext_vector_type(4)));
typedef short s8_t __attribute__((ext_vector_type(8)));   // 8 bf16 (4 VGPRs)

// d_out layout (floats):
// h1: [0, ND)  h2: [ND, 2*ND)  c1c2: [2*ND, 2*ND+128)  h3: [2*ND+128, ...)  h4: [3*ND+128, ...)

#define NBUCK 98                   // buckets of 1024 nodes; 98*1024 >= 100000
#define BCAP 13312                 // fixed bucket region (mean 10240, sd ~101; +30 sigma)
#define OFFSTR 1028                // per-bucket off-table stride (16B aligned; 1025 used)

// d_ws layout (4-byte words):
#define WS_OFF1  200000            // 98*1028 = 100744
#define WS_OFF2  300744
#define WS_SORT1 401488            // 98*13312 = 1,304,576 (payloads then sorted src ids)
#define WS_SORT2 1706064
#define WS_CSUM  3010640           // 128 floats
#define WS_BCUR  3010768           // 196 zero-based partition cursors
#define WS_WBT   3010964           // bf16 W^T: WbT[g][col][k], 8192 ushort = 4096 words
#define WS_FBSB  3015060           // interleaved bf16 rows: [FB(128B) | SB(128B)] per node
#define WS_END   (WS_FBSB + 6400000) // ~37.7 MB

#define CH_CONV 3125               // convert blocks: 3125*256*16 floats = 12.8M
#define CH_PARTG 489               // partition blocks per graph: 489*512 int4 >= 250000

__device__ __forceinline__ unsigned pk_bf16(float a, float b) {
    __hip_bfloat16 ha = __float2bfloat16(a), hb = __float2bfloat16(b);
    return (unsigned)(*(unsigned short*)&ha) | ((unsigned)(*(unsigned short*)&hb) << 16);
}
__device__ __forceinline__ float bf_lo(unsigned u) { return __uint_as_float(u << 16); }
__device__ __forceinline__ float bf_hi(unsigned u) { return __uint_as_float(u & 0xFFFF0000u); }

__global__ __launch_bounds__(256) void k_init(int* __restrict__ ws,
                                              const float* __restrict__ W1,
                                              const float* __restrict__ W2) {
    const int t = threadIdx.x;
    if (t < 128) ((float*)ws)[WS_CSUM + t] = 0.f;
    if (t < 196) ws[WS_BCUR + t] = 0;
    // W -> bf16 transposed: WbT[g][col][k]
    unsigned short* wbt = (unsigned short*)(ws + WS_WBT);
    for (int i = t; i < 8192; i += 256) {
        const int g = i >> 12, e = i & 4095;
        const int col = e >> 6, k = e & 63;
        const float* Wsrc = g ? W2 : W1;
        __hip_bfloat16 hb = __float2bfloat16(Wsrc[k * 64 + col]);
        wbt[i] = *(unsigned short*)&hb;
    }
}

// FUSED f32->bf16 convert (into interleaved FBSB rows) + partition.
__global__ __launch_bounds__(256) void k_convert_partition(
    const f4_t* __restrict__ feat4, const f4_t* __restrict__ shuf4,
    const int4* __restrict__ src1, const int4* __restrict__ dst1,
    const int4* __restrict__ src2, const int4* __restrict__ dst2,
    int* __restrict__ ws) {
    const int bid = blockIdx.x;
    const int t = threadIdx.x;
    if (bid < CH_CONV) {
        // ---------------- convert ----------------
        const long long NF4 = ND / 4;               // 1.6M f4 per array
        const long long base = ((long long)bid * 256 + t) * 4;
        uint2* T2 = (uint2*)(ws + WS_FBSB);         // row = 32 uint2 (256B)
        #pragma unroll
        for (int k = 0; k < 4; ++k) {
            const long long j = base + k;
            if (j < NF4) {
                const f4_t v = __builtin_nontemporal_load(feat4 + j);
                const long long n = j >> 4, c = j & 15;
                T2[n * 32 + c] = make_uint2(pk_bf16(v.x, v.y), pk_bf16(v.z, v.w));
            } else if (j < 2 * NF4) {
                const long long jj = j - NF4;
                const f4_t v = __builtin_nontemporal_load(shuf4 + jj);
                const long long n = jj >> 4, c = jj & 15;
                T2[n * 32 + 16 + c] = make_uint2(pk_bf16(v.x, v.y), pk_bf16(v.z, v.w));
            }
        }
    } else {
        // ---------------- partition ----------------
        const int pid = bid - CH_CONV;
        const int g = pid >= CH_PARTG;
        const int px = g ? pid - CH_PARTG : pid;
        __shared__ int lcnt[NBUCK];
        __shared__ int lbase[NBUCK];
        const int4* sv4 = g ? src2 : src1;
        const int4* dv4 = g ? dst2 : dst1;
        int* sortp = ws + (g ? WS_SORT2 : WS_SORT1);
        int* bcur = ws + WS_BCUR + g * NBUCK;
        const int Q = N_EDGES / 4;

        const int q0 = px * 512 + t;
        const int q1 = q0 + 256;
        const bool v0 = q0 < Q, v1 = q1 < Q;
        int4 s0, d0, s1, d1;
        if (v0) { s0 = sv4[q0]; d0 = dv4[q0]; }
        if (v1) { s1 = sv4[q1]; d1 = dv4[q1]; }

        for (int i = t; i < NBUCK; i += 256) lcnt[i] = 0;
        __syncthreads();
        if (v0) {
            atomicAdd(&lcnt[d0.x >> 10], 1); atomicAdd(&lcnt[d0.y >> 10], 1);
            atomicAdd(&lcnt[d0.z >> 10], 1); atomicAdd(&lcnt[d0.w >> 10], 1);
        }
        if (v1) {
            atomicAdd(&lcnt[d1.x >> 10], 1); atomicAdd(&lcnt[d1.y >> 10], 1);
            atomicAdd(&lcnt[d1.z >> 10], 1); atomicAdd(&lcnt[d1.w >> 10], 1);
        }
        __syncthreads();
        if (t < NBUCK) lbase[t] = lcnt[t] ? t * BCAP + atomicAdd(&bcur[t], lcnt[t]) : 0;
        __syncthreads();

#define PUT(ss, dd) { const int b_ = (dd) >> 10; \
    const int pos_ = atomicAdd(&lbase[b_], 1); \
    sortp[pos_] = (ss) | (((dd) & 1023) << 17); }
        if (v0) { PUT(s0.x, d0.x); PUT(s0.y, d0.y); PUT(s0.z, d0.z); PUT(s0.w, d0.w); }
        if (v1) { PUT(s1.x, d1.x); PUT(s1.y, d1.y); PUT(s1.z, d1.z); PUT(s1.w, d1.w); }
#undef PUT
    }
}

// Place: one block per (bucket, graph).
__global__ __launch_bounds__(256) void k_place(int* __restrict__ ws) {
    const int g = blockIdx.y;
    const int b = blockIdx.x;
    const int t = threadIdx.x;
    __shared__ int pl[BCAP];
    __shared__ int lcur[1024];
    __shared__ int sscan[256];

    const int base = b * BCAP;
    int cnt = ws[WS_BCUR + g * NBUCK + b];
    if (cnt > BCAP) cnt = BCAP;
    int* sortp = ws + (g ? WS_SORT2 : WS_SORT1);
    int* off = ws + (g ? WS_OFF2 : WS_OFF1) + b * OFFSTR;

    for (int i = t; i < cnt; i += 256) pl[i] = sortp[base + i];
    for (int i = t; i < 1024; i += 256) lcur[i] = 0;
    __syncthreads();
    for (int i = t; i < cnt; i += 256) atomicAdd(&lcur[(pl[i] >> 17) & 1023], 1);
    __syncthreads();

    const int c0 = lcur[4 * t], c1 = lcur[4 * t + 1], c2 = lcur[4 * t + 2], c3 = lcur[4 * t + 3];
    sscan[t] = c0 + c1 + c2 + c3;
    __syncthreads();
    for (int d = 1; d < 256; d <<= 1) {
        int v = 0;
        if (t >= d) v = sscan[t - d];
        __syncthreads();
        sscan[t] += v;
        __syncthreads();
    }
    const int excl = (t == 0) ? 0 : sscan[t - 1];
    const int p0 = base + excl, p1 = p0 + c0, p2 = p1 + c1, p3 = p2 + c2;
    lcur[4 * t] = p0; lcur[4 * t + 1] = p1; lcur[4 * t + 2] = p2; lcur[4 * t + 3] = p3;
    *(int4*)(off + 4 * t) = make_int4(p0, p1, p2, p3);   // off[0..1023]
    if (t == 255) off[1024] = base + cnt;                // bucket end sentinel
    __syncthreads();
    for (int i = t; i < cnt; i += 256) {
        const int p = pl[i];
        const int pos = atomicAdd(&lcur[(p >> 17) & 1023], 1);
        sortp[pos] = p & 0x1FFFF;
    }
}

// PURE gather over the interleaved FBSB table (each edge = 2x16B in ONE 256B
// row). One node per 8-lane group; unroll-8. Packed-agg stores are REGULAR
// (cacheable): k_htrans_mfma re-reads them immediately, so L3 should serve
// that 51MB (R19 A/B showed NT-vs-regular doesn't change the gather's FETCH).
#define ACC2(gv, sv) \
    ag[0] += bf_lo(gv.x); ag[1] += bf_hi(gv.x); \
    ag[2] += bf_lo(gv.y); ag[3] += bf_hi(gv.y); \
    ag[4] += bf_lo(gv.z); ag[5] += bf_hi(gv.z); \
    ag[6] += bf_lo(gv.w); ag[7] += bf_hi(gv.w); \
    as[0] += bf_lo(sv.x); as[1] += bf_hi(sv.x); \
    as[2] += bf_lo(sv.y); as[3] += bf_hi(sv.y); \
    as[4] += bf_lo(sv.z); as[5] += bf_hi(sv.z); \
    as[6] += bf_lo(sv.w); as[7] += bf_hi(sv.w);

__global__ __launch_bounds__(256) void k_gather(int* __restrict__ ws,
                                                float* __restrict__ out) {
    const int g = blockIdx.y;
    const int* offT   = ws + (g ? WS_OFF2 : WS_OFF1);
    const int* sorted = ws + (g ? WS_SORT2 : WS_SORT1);
    const uint4* T = (const uint4*)(ws + WS_FBSB);   // 16 uint4 per row
    float* h_f = out + (g ? ND : 0);
    float* h_s = out + (g ? 3 * ND + 128 : 2 * ND + 128);

    const int t = threadIdx.x;
    const int wave = t >> 6;
    const int lane = t & 63;
    const int nslot = lane >> 3;
    const int sub = lane & 7;

    const int n = blockIdx.x * 32 + wave * 8 + nslot;
    if (n >= N_NODES) return;

    float ag[8] = {0.f, 0.f, 0.f, 0.f, 0.f, 0.f, 0.f, 0.f};
    float as[8] = {0.f, 0.f, 0.f, 0.f, 0.f, 0.f, 0.f, 0.f};

    const int* offb = offT + (n >> 10) * OFFSTR + (n & 1023);
    const int e0 = offb[0];
    const int e1 = offb[1];
    int e = e0;
    for (; e + 7 < e1; e += 8) {
        const int sA = sorted[e],     sB = sorted[e + 1];
        const int sC = sorted[e + 2], sD = sorted[e + 3];
        const int sE = sorted[e + 4], sF = sorted[e + 5];
        const int sG = sorted[e + 6], sH = sorted[e + 7];
        const uint4 gA = T[sA * 16 + sub], hA = T[sA * 16 + 8 + sub];
        const uint4 gB = T[sB * 16 + sub], hB = T[sB * 16 + 8 + sub];
        const uint4 gC = T[sC * 16 + sub], hC = T[sC * 16 + 8 + sub];
        const uint4 gD = T[sD * 16 + sub], hD = T[sD * 16 + 8 + sub];
        const uint4 gE = T[sE * 16 + sub], hE = T[sE * 16 + 8 + sub];
        const uint4 gF = T[sF * 16 + sub], hF = T[sF * 16 + 8 + sub];
        const uint4 gG = T[sG * 16 + sub], hG = T[sG * 16 + 8 + sub];
        const uint4 gH = T[sH * 16 + sub], hH = T[sH * 16 + 8 + sub];
        ACC2(gA, hA); ACC2(gB, hB); ACC2(gC, hC); ACC2(gD, hD);
        ACC2(gE, hE); ACC2(gF, hF); ACC2(gG, hG); ACC2(gH, hH);
    }
    for (; e + 3 < e1; e += 4) {
        const int sA = sorted[e],     sB = sorted[e + 1];
        const int sC = sorted[e + 2], sD = sorted[e + 3];
        const uint4 gA = T[sA * 16 + sub], hA = T[sA * 16 + 8 + sub];
        const uint4 gB = T[sB * 16 + sub], hB = T[sB * 16 + 8 + sub];
        const uint4 gC = T[sC * 16 + sub], hC = T[sC * 16 + 8 + sub];
        const uint4 gD = T[sD * 16 + sub], hD = T[sD * 16 + 8 + sub];
        ACC2(gA, hA); ACC2(gB, hB); ACC2(gC, hC); ACC2(gD, hD);
    }
    for (; e < e1; ++e) {
        const int s = sorted[e];
        const uint4 gv = T[s * 16 + sub], hv = T[s * 16 + 8 + sub];
        ACC2(gv, hv);
    }

    uint4 pf;
    pf.x = pk_bf16(ag[0], ag[1]); pf.y = pk_bf16(ag[2], ag[3]);
    pf.z = pk_bf16(ag[4], ag[5]); pf.w = pk_bf16(ag[6], ag[7]);
    ((uint4*)(h_f + (long long)n * DIM))[sub] = pf;
    uint4 ps;
    ps.x = pk_bf16(as[0], as[1]); ps.y = pk_bf16(as[2], as[3]);
    ps.z = pk_bf16(as[4], as[5]); ps.w = pk_bf16(as[6], as[7]);
    ((uint4*)(h_s + (long long)n * DIM))[sub] = ps;
}

// MFMA transform: h = agg_bf16 @ W_bf16 + b, in place. REGULAR scalar h-stores
// (R19 lesson: 4B nontemporal stores defeat write-combining, +12us).
__global__ __launch_bounds__(256) void k_htrans_mfma(int* __restrict__ ws,
                                                     const float* __restrict__ b1,
                                                     const float* __restrict__ b2,
                                                     float* __restrict__ out) {
    const int y = blockIdx.y;
    const int g = y & 1;
    float* hreg = out + (y == 0 ? 0 : y == 1 ? ND
                       : y == 2 ? 2 * ND + 128 : 3 * ND + 128);
    const float* bias = g ? b2 : b1;
    const s8_t* WT = (const s8_t*)((const unsigned short*)(ws + WS_WBT) + g * 4096);
    float* csum = (float*)ws + WS_CSUM + y * 64;   // only used for y<2

    __shared__ float red[4][64];

    const int t = threadIdx.x;
    const int wave = t >> 6;
    const int lane = t & 63;
    const int lm = lane & 15;
    const int lh = lane >> 4;

    s8_t bfr[4][2];
    #pragma unroll
    for (int nt = 0; nt < 4; ++nt) {
        bfr[nt][0] = WT[(nt * 16 + lm) * 8 + lh];
        bfr[nt][1] = WT[(nt * 16 + lm) * 8 + 4 + lh];
    }
    float bs[4];
    #pragma unroll
    for (int nt = 0; nt < 4; ++nt) bs[nt] = bias[nt * 16 + lm];

    float csloc[4] = {0.f, 0.f, 0.f, 0.f};
    const int r0base = blockIdx.x * 256 + wave * 64;

    #pragma unroll
    for (int tile = 0; tile < 4; ++tile) {
        const int r0 = r0base + tile * 16;
        const int rowA = r0 + lm;
        const int rA = rowA < N_NODES ? rowA : N_NODES - 1;   // clamp (no OOB read)
        const s8_t* arow = (const s8_t*)(hreg + (long long)rA * DIM);
        const s8_t a0 = arow[lh];       // k = 0..31 chunk
        const s8_t a1 = arow[4 + lh];   // k = 32..63 chunk

        f4_t acc[4];
        #pragma unroll
        for (int nt = 0; nt < 4; ++nt) {
            acc[nt] = (f4_t){0.f, 0.f, 0.f, 0.f};
            acc[nt] = __builtin_amdgcn_mfma_f32_16x16x32_bf16(a0, bfr[nt][0], acc[nt], 0, 0, 0);
            acc[nt] = __builtin_amdgcn_mfma_f32_16x16x32_bf16(a1, bfr[nt][1], acc[nt], 0, 0, 0);
        }
        #pragma unroll
        for (int nt = 0; nt < 4; ++nt) {
            #pragma unroll
            for (int i = 0; i < 4; ++i) {
                const int row = r0 + 4 * lh + i;
                if (row < N_NODES) {
                    const float v = acc[nt][i] + bs[nt];
                    hreg[(long long)row * DIM + nt * 16 + lm] = v;
                    csloc[nt] += v;
                }
            }
        }
    }

    if (y < 2) {
        #pragma unroll
        for (int nt = 0; nt < 4; ++nt) {
            csloc[nt] += __shfl_xor(csloc[nt], 16);
            csloc[nt] += __shfl_xor(csloc[nt], 32);
        }
        if (lane < 16) {
            #pragma unroll
            for (int nt = 0; nt < 4; ++nt) red[wave][nt * 16 + lane] = csloc[nt];
        }
        __syncthreads();
        if (t < 64) {
            const float s = red[0][t] + red[1][t] + red[2][t] + red[3][t];
            unsafeAtomicAdd(&csum[t], s);
        }
    }
}

__global__ void k_final(const float* __restrict__ ws_csum, float* __restrict__ out_c) {
    int t = threadIdx.x;  // 0..63 -> c1, 64..127 -> c2
    float m = ws_csum[t] * (1.0f / (float)N_NODES);
    out_c[t] = 1.f / (1.f + expf(-m));
}

extern "C" void kernel_launch(void* const* d_in, const int* in_sizes, int n_in,
                              void* d_out, int out_size, void* d_ws, size_t ws_size,
                              hipStream_t stream) {
    const float* feat = (const float*)d_in[0];
    const float* shuf = (const float*)d_in[1];
    const int* src1 = (const int*)d_in[2];
    const int* dst1 = (const int*)d_in[3];
    const int* src2 = (const int*)d_in[4];
    const int* dst2 = (const int*)d_in[5];
    const float* W1 = (const float*)d_in[6];
    const float* b1 = (const float*)d_in[7];
    const float* W2 = (const float*)d_in[8];
    const float* b2 = (const float*)d_in[9];

    float* out = (float*)d_out;
    int* ws = (int*)d_ws;
    float* ws_f = (float*)d_ws;
    float* c_out = out + 2 * ND;

    k_init<<<1, 256, 0, stream>>>(ws, W1, W2);
    k_convert_partition<<<CH_CONV + 2 * CH_PARTG, 256, 0, stream>>>(
        (const f4_t*)feat, (const f4_t*)shuf,
        (const int4*)src1, (const int4*)dst1, (const int4*)src2, (const int4*)dst2, ws);
    k_place<<<dim3(NBUCK, 2), 256, 0, stream>>>(ws);
    k_gather<<<dim3((N_NODES + 31) / 32, 2), 256, 0, stream>>>(ws, out);
    k_htrans_mfma<<<dim3((N_NODES + 255) / 256, 4), 256, 0, stream>>>(ws, b1, b2, out);
    k_final<<<1, 128, 0, stream>>>(ws_f + WS_CSUM, c_out);
}